// Round 5
// baseline (5596.172 us; speedup 1.0000x reference)
//
#include <hip/hip_runtime.h>

// Problem constants (fixed by the reference): B=64, T=512, D=1024, R=1024, O=1024
#define BB 64
#define TT 512
#define DD 1024
#define RR 1024

#define SCAN_BLOCKS 32
#define SCAN_LDS_BYTES 131072   // hs: [128 c8][64 rows] x 16B (chunk-major, no pad)

typedef __bf16 bf16x8 __attribute__((ext_vector_type(8)));
typedef float f32x4 __attribute__((ext_vector_type(4)));
typedef unsigned short us4 __attribute__((ext_vector_type(4)));
typedef unsigned short us8 __attribute__((ext_vector_type(8)));
typedef unsigned int u32x4 __attribute__((ext_vector_type(4)));
typedef unsigned long long u64;

__device__ inline unsigned short f2bf(float f) {
  unsigned int u = __float_as_uint(f);
  u = (u + 0x7fffu + ((u >> 16) & 1u)) >> 16;   // RNE
  return (unsigned short)u;
}
__device__ inline float bf2f(unsigned short b) {
  return __uint_as_float(((unsigned int)b) << 16);
}

// Coherent 16B store: sc0 sc1 -> write-through to coherence point (L3).
__device__ inline void st16_sc(void* p, u32x4 v) {
  asm volatile("global_store_dwordx4 %0, %1, off sc0 sc1" :: "v"(p), "v"(v) : "memory");
}

// ---- fp32 -> bf16 vectorized convert (n4 = n/4 groups) ----
__global__ void k_f2b4(const float* __restrict__ in, unsigned short* __restrict__ out, int n4) {
  int i = blockIdx.x * blockDim.x + threadIdx.x;
  if (i < n4) {
    const float4 v = ((const float4*)in)[i];
    us4 o;
    o.x = f2bf(v.x); o.y = f2bf(v.y); o.z = f2bf(v.z); o.w = f2bf(v.w);
    ((us4*)out)[i] = o;
  }
}

// ---- transpose 1024x1024 fp32 -> bf16 (out[j][k] = in[k][j]) ----
__global__ __launch_bounds__(256) void k_transpose_bf16(
    const float* __restrict__ in, unsigned short* __restrict__ out) {
  __shared__ float tile[32][33];
  const int bx = blockIdx.x * 32, by0 = blockIdx.y * 32;
  const int tx = threadIdx.x, ty = threadIdx.y;  // block (32,8)
#pragma unroll
  for (int r = 0; r < 32; r += 8)
    tile[ty + r][tx] = in[(size_t)(by0 + ty + r) * 1024 + bx + tx];
  __syncthreads();
#pragma unroll
  for (int r = 0; r < 32; r += 8)
    out[(size_t)(bx + ty + r) * 1024 + by0 + tx] = f2bf(tile[tx][ty + r]);
}

// ---- async global->LDS, 16B per lane (plain cached, for the GEMM kernels) ----
__device__ inline void gload_lds16(const unsigned short* g, unsigned short* l) {
  __builtin_amdgcn_global_load_lds(
      (const __attribute__((address_space(1))) unsigned int*)g,
      (__attribute__((address_space(3))) unsigned int*)l, 16, 0, 0);
}
// Coherent variant: aux=0x11 = sc0|sc1 (gfx940+ CPol: bit0=sc0, bit4=sc1).
__device__ inline void gload_lds16_sc(const unsigned short* g, unsigned short* l) {
  __builtin_amdgcn_global_load_lds(
      (const __attribute__((address_space(1))) unsigned int*)g,
      (__attribute__((address_space(3))) unsigned int*)l, 16, 0, 17);
}

// ---- bf16 GEMM, C[m,n] = sum_k A[m,k]*B[n,k], 128x128 tile, BK=32 ----
// EPI==0: out = xhz time-major [T][B][2048] bf16, bias folded (bh n<1024, bz else)
// EPI==1: out[m*1024+n] bf16 (Mz into Wrec rows 1024..2047)
template <int EPI>
__global__ __launch_bounds__(256) void gemm_bt(
    const unsigned short* __restrict__ A,
    const unsigned short* __restrict__ Bm,
    const float* __restrict__ bias_h,
    const float* __restrict__ bias_z,
    unsigned short* __restrict__ outb, int K) {
  __shared__ __attribute__((aligned(16))) unsigned short As[128 * 32];
  __shared__ __attribute__((aligned(16))) unsigned short Bs[128 * 32];
  const int tid = threadIdx.x;
  const int m0 = blockIdx.y * 128, n0 = blockIdx.x * 128;
  const int lane = tid & 63, wid = tid >> 6;
  const int l16 = lane & 15, quad = lane >> 4;
  const int wm = (wid & 1) * 64, wn = (wid >> 1) * 64;

  f32x4 acc[4][4] = {};

  const int c0 = tid, c1 = 256 + tid;
  const int rowA0 = c0 >> 2, colA0 = (c0 & 3) << 3;
  const int rowA1 = c1 >> 2, colA1 = (c1 & 3) << 3;

  for (int kk = 0; kk < K; kk += 32) {
    __syncthreads();
    gload_lds16(A + (size_t)(m0 + rowA0) * K + kk + colA0, As + c0 * 8);
    gload_lds16(A + (size_t)(m0 + rowA1) * K + kk + colA1, As + c1 * 8);
    gload_lds16(Bm + (size_t)(n0 + rowA0) * K + kk + colA0, Bs + c0 * 8);
    gload_lds16(Bm + (size_t)(n0 + rowA1) * K + kk + colA1, Bs + c1 * 8);
    __syncthreads();
    bf16x8 af[4], bfr[4];
#pragma unroll
    for (int i = 0; i < 4; ++i) {
      af[i] = *(const bf16x8*)&As[(wm + i * 16 + l16) * 32 + quad * 8];
      bfr[i] = *(const bf16x8*)&Bs[(wn + i * 16 + l16) * 32 + quad * 8];
    }
#pragma unroll
    for (int i = 0; i < 4; ++i)
#pragma unroll
      for (int j = 0; j < 4; ++j)
        acc[i][j] = __builtin_amdgcn_mfma_f32_16x16x32_bf16(af[i], bfr[j], acc[i][j], 0, 0, 0);
  }

#pragma unroll
  for (int i = 0; i < 4; ++i) {
#pragma unroll
    for (int j = 0; j < 4; ++j) {
#pragma unroll
      for (int r = 0; r < 4; ++r) {
        const int m = m0 + wm + i * 16 + quad * 4 + r;
        const int n = n0 + wn + j * 16 + l16;
        float v = acc[i][j][r];
        if (EPI == 0) {
          v += (n < 1024) ? bias_h[n] : bias_z[n - 1024];
          const int b = m >> 9;          // m = b*T + t, T=512
          const int t = m & 511;
          outb[((size_t)(t * 64 + b) << 11) + n] = f2bf(v);
        } else {
          outb[(size_t)m * 1024 + n] = f2bf(v);
        }
      }
    }
  }
}

// ---- persistent scan over T=512 steps + output GEMM ----
// 32 blocks x 1024 threads. 16 waves = 4 K-slices (ks) x 2 m-halves (ms) x
// 2 n-halves (ns). Block g owns h-cols [g*32,+32); local n-col c<32 -> Whh
// row i0+c (ph), c>=32 -> Mz row 1024+i0+(c-32) (pz).
//
// Round-5 structure:
//  * h staged global->LDS via coherent DMA (global_load_lds aux=sc0|sc1),
//    chunk-major layout hs[c8][row] (c8=k/8) satisfying the lane-contiguous
//    LDS-dst constraint; no staging VGPRs, no ds_writes.
//  * (4,2,2) tiling: each A-fragment read feeds 2 MFMAs -> A-read traffic
//    halved vs r4 (256 KB/block/step).
//  * No block-wide barrier: wave w's K-slice needs only producer blocks
//    2w,2w+1 -> per-wave poll of 2 flags before its own DMA (dataflow).
//    2 h buffers remain race-free: any block's stage transitively requires
//    all 32 flags >= tt, so writes of h_{t+2} can't pass pending reads of h_t.
__global__ __launch_bounds__(1024) void scan_out_k(
    const unsigned short* __restrict__ xhz,   // [T][B][2048] bf16
    const unsigned short* __restrict__ Wrec,  // [2048][1024] bf16 (Whh ; Mz)
    const unsigned short* __restrict__ Wyb,   // [1024][1024] bf16
    const float* __restrict__ by,
    unsigned short* __restrict__ hb0, unsigned short* __restrict__ hb1,
    unsigned int* __restrict__ flags,
    float* __restrict__ out) {
  extern __shared__ char smem[];
  unsigned short* hs = (unsigned short*)smem;   // [128][64] x 8 bf16
  float* red = (float*)smem;                    // overlay [4][64][68] f32

  const int tid = threadIdx.x, g = blockIdx.x;
  const int lane = tid & 63, w = tid >> 6;
  const int l16 = lane & 15, quad = lane >> 4;
  const int ks = w >> 2, ms = (w >> 1) & 1, ns = w & 1;
  const int kw = ks * 256;
  const int i0 = g * 32;

  // loop-invariant B fragments: bfr[s][nf], 64 VGPRs (plain cached loads)
  bf16x8 bfr[8][2];
#pragma unroll
  for (int nf = 0; nf < 2; ++nf) {
    const int brow = (ns == 0) ? (i0 + nf * 16 + l16) : (1024 + i0 + nf * 16 + l16);
    const unsigned short* Bp = Wrec + (size_t)brow * 1024 + kw + quad * 8;
#pragma unroll
    for (int s = 0; s < 8; ++s) bfr[s][nf] = *(const bf16x8*)(Bp + s * 32);
  }

  // producer poll setup: wave w consumes h-cols [w*64,(w+1)*64) = blocks 2w,2w+1
  const int pidx = 2 * w + (lane & 1);
  const bool polls = (lane < 2);

  // elementwise ownership (threads 0..255): b = tid>>2, cols i0+oc8..+8
  const int eb = tid >> 2, oc8 = (tid & 3) * 8;
  float hold[8] = {0.f, 0.f, 0.f, 0.f, 0.f, 0.f, 0.f, 0.f};

  const unsigned short* hbc = hb0;
  unsigned short* hbn = hb1;

  for (int tt = 0; tt < TT; ++tt) {
    // ---- per-wave producer poll: h_tt slices from blocks 2w,2w+1 ready? ----
    {
      const unsigned int tgt = (unsigned int)tt;
      unsigned int v;
      do {
        v = polls ? __hip_atomic_load(&flags[pidx], __ATOMIC_RELAXED, __HIP_MEMORY_SCOPE_AGENT)
                  : 0xffffffffu;
      } while (__any(v < tgt));
    }
    // ---- coherent DMA stage: wave w fills c8 = w*8 .. w*8+7 ----
#pragma unroll
    for (int j = 0; j < 8; ++j) {
      const int c8 = w * 8 + j;
      gload_lds16_sc(hbc + (size_t)lane * 1024 + c8 * 8, hs + c8 * 512);
    }
    // xhz prefetch (plain cached)
    u32x4 xh8 = {}, xz8 = {};
    if (tid < 256) {
      const size_t xrow = ((size_t)(tt * 64 + eb)) << 11;
      xh8 = *(const u32x4*)(xhz + xrow + i0 + oc8);
      xz8 = *(const u32x4*)(xhz + xrow + 1024 + i0 + oc8);
    }
    __syncthreads();   // drains DMA vmcnt -> hs fully staged

    // ---- MFMA: each A-read feeds 2 n-frags ----
    f32x4 acc[2][2] = {};
#pragma unroll
    for (int s = 0; s < 8; ++s) {
      const int c8 = ks * 32 + s * 4 + quad;
#pragma unroll
      for (int mt = 0; mt < 2; ++mt) {
        const int row = ms * 32 + mt * 16 + l16;
        const bf16x8 afr = *(const bf16x8*)(hs + c8 * 512 + row * 8);
        acc[mt][0] = __builtin_amdgcn_mfma_f32_16x16x32_bf16(afr, bfr[s][0], acc[mt][0], 0, 0, 0);
        acc[mt][1] = __builtin_amdgcn_mfma_f32_16x16x32_bf16(afr, bfr[s][1], acc[mt][1], 0, 0, 0);
      }
    }
    __syncthreads();   // hs reads done; safe to overlay red

    // ---- K-partials into LDS: red[ks][m 0..63][c 0..63], stride 68 ----
#pragma unroll
    for (int mt = 0; mt < 2; ++mt)
#pragma unroll
      for (int nf = 0; nf < 2; ++nf)
#pragma unroll
        for (int r = 0; r < 4; ++r)
          red[(size_t)(ks * 64 + ms * 32 + mt * 16 + quad * 4 + r) * 68 +
              ns * 32 + nf * 16 + l16] = acc[mt][nf][r];
    __syncthreads();

    // ---- elementwise update: threads 0..255, 8 cols each ----
    if (tid < 256) {
      float ph[8] = {}, pz[8] = {};
#pragma unroll
      for (int k = 0; k < 4; ++k) {
        const float* rb = red + (size_t)(k * 64 + eb) * 68;
        const float4 a0 = *(const float4*)(rb + oc8);
        const float4 a1 = *(const float4*)(rb + oc8 + 4);
        const float4 c0 = *(const float4*)(rb + 32 + oc8);
        const float4 c1 = *(const float4*)(rb + 32 + oc8 + 4);
        ph[0] += a0.x; ph[1] += a0.y; ph[2] += a0.z; ph[3] += a0.w;
        ph[4] += a1.x; ph[5] += a1.y; ph[6] += a1.z; ph[7] += a1.w;
        pz[0] += c0.x; pz[1] += c0.y; pz[2] += c0.z; pz[3] += c0.w;
        pz[4] += c1.x; pz[5] += c1.y; pz[6] += c1.z; pz[7] += c1.w;
      }
      unsigned short hb16[8];
#pragma unroll
      for (int j = 0; j < 8; ++j) {
        const float xh = bf2f((unsigned short)((j < 4 ? xh8[j] : 0), ((const unsigned short*)&xh8)[j]));
        const float xz = bf2f(((const unsigned short*)&xz8)[j]);
        const float z = 1.0f / (1.0f + __expf(-(xz + pz[j])));
        const float hbv = fmaxf(xh + ph[j], 0.0f);
        hold[j] = z * hold[j] + (1.0f - z) * hbv;
        hb16[j] = f2bf(hold[j]);
      }
      u32x4 pk;
#pragma unroll
      for (int j = 0; j < 4; ++j)
        pk[j] = (unsigned int)hb16[2 * j] | ((unsigned int)hb16[2 * j + 1] << 16);
      st16_sc(hbn + (size_t)eb * 1024 + i0 + oc8, pk);
    }
    __syncthreads();   // drains the sc stores (vmcnt) for waves 0..3
    if (tid == 0)
      __hip_atomic_store(&flags[g], (unsigned int)(tt + 1),
                         __ATOMIC_RELAXED, __HIP_MEMORY_SCOPE_AGENT);

    const unsigned short* tc = hbc; hbc = hbn; hbn = (unsigned short*)tc;
  }

  // ---- epilogue: out = h_final @ Wy^T + by (h_512 in hbc == hb0) ----
  {
    const unsigned int tgt = (unsigned int)TT;
    unsigned int v;
    do {
      v = polls ? __hip_atomic_load(&flags[pidx], __ATOMIC_RELAXED, __HIP_MEMORY_SCOPE_AGENT)
                : 0xffffffffu;
    } while (__any(v < tgt));
  }
#pragma unroll
  for (int j = 0; j < 8; ++j) {
    const int c8 = w * 8 + j;
    gload_lds16_sc(hbc + (size_t)lane * 1024 + c8 * 8, hs + c8 * 512);
  }
  __syncthreads();

  // wave (ks,ms,ns): out-cols i0 + ns*16 + l16 (32 per block), rows ms*32+...
  {
    const int ocol = i0 + ns * 16 + l16;
    const unsigned short* Byp = Wyb + (size_t)ocol * 1024 + kw + quad * 8;
    bf16x8 bfr2[8];
#pragma unroll
    for (int s = 0; s < 8; ++s) bfr2[s] = *(const bf16x8*)(Byp + s * 32);
    f32x4 acc2[2] = {};
#pragma unroll
    for (int s = 0; s < 8; ++s) {
      const int c8 = ks * 32 + s * 4 + quad;
#pragma unroll
      for (int mt = 0; mt < 2; ++mt) {
        const int row = ms * 32 + mt * 16 + l16;
        const bf16x8 afr = *(const bf16x8*)(hs + c8 * 512 + row * 8);
        acc2[mt] = __builtin_amdgcn_mfma_f32_16x16x32_bf16(afr, bfr2[s], acc2[mt], 0, 0, 0);
      }
    }
    __syncthreads();   // hs reads done; overlay red2
    float* red2 = (float*)smem;   // [4][64][36]
#pragma unroll
    for (int mt = 0; mt < 2; ++mt)
#pragma unroll
      for (int r = 0; r < 4; ++r)
        red2[(size_t)(ks * 64 + ms * 32 + mt * 16 + quad * 4 + r) * 36 + ns * 16 + l16] = acc2[mt][r];
  }
  __syncthreads();
  {
    float* red2 = (float*)smem;
    const int b = tid >> 4, oc2 = (tid & 15) * 2;
    float o0 = by[i0 + oc2], o1 = by[i0 + oc2 + 1];
#pragma unroll
    for (int k = 0; k < 4; ++k) {
      const float* rb = red2 + (size_t)(k * 64 + b) * 36;
      o0 += rb[oc2]; o1 += rb[oc2 + 1];
    }
    float2 ov; ov.x = o0; ov.y = o1;
    *(float2*)(out + (size_t)b * 1024 + i0 + oc2) = ov;
  }
}

extern "C" void kernel_launch(void* const* d_in, const int* in_sizes, int n_in,
                              void* d_out, int out_size, void* d_ws, size_t ws_size,
                              hipStream_t stream) {
  const float* x = (const float*)d_in[0];
  const float* Wxh = (const float*)d_in[1];
  const float* bh = (const float*)d_in[2];
  const float* Whh = (const float*)d_in[3];
  const float* Wxz = (const float*)d_in[4];
  const float* bz = (const float*)d_in[5];
  const float* Whz = (const float*)d_in[6];
  const float* Wy = (const float*)d_in[7];
  const float* by = (const float*)d_in[8];
  float* out = (float*)d_out;

  char* ws = (char*)d_ws;
  size_t off = 0;
  auto alloc = [&](size_t bytes) -> void* {
    void* p = ws + off;
    off += (bytes + 255) & ~(size_t)255;
    return p;
  };
  const size_t nX = (size_t)BB * TT * DD;  // 33554432
  unsigned short* xb = (unsigned short*)alloc(nX * 2);                  // x bf16
  unsigned short* Wcat = (unsigned short*)alloc((size_t)2048 * 1024 * 2);  // [Wxh;Wxz]
  unsigned short* WhzT = (unsigned short*)alloc((size_t)1024 * 1024 * 2);  // Whz^T
  unsigned short* Wrec = (unsigned short*)alloc((size_t)2048 * 1024 * 2);  // [Whh;Mz]
  unsigned short* Wyb = (unsigned short*)alloc((size_t)1024 * 1024 * 2);   // Wy bf16
  unsigned short* xhz = (unsigned short*)alloc((size_t)TT * BB * 2048 * 2);  // 128 MB
  unsigned short* hb0 = (unsigned short*)alloc((size_t)BB * RR * 2);
  unsigned short* hb1 = (unsigned short*)alloc((size_t)BB * RR * 2);
  unsigned int* flags = (unsigned int*)alloc(1024);

  hipMemsetAsync(hb0, 0, (size_t)BB * RR * 2, stream);
  hipMemsetAsync(flags, 0, 1024, stream);

  // weight / input conversions
  k_f2b4<<<dim3((unsigned)(nX / 4 / 256)), 256, 0, stream>>>(x, xb, (int)(nX / 4));
  k_f2b4<<<dim3(1024), 256, 0, stream>>>(Wxh, Wcat, 262144);
  k_f2b4<<<dim3(1024), 256, 0, stream>>>(Wxz, Wcat + 1024 * 1024, 262144);
  k_f2b4<<<dim3(1024), 256, 0, stream>>>(Whh, Wrec, 262144);
  k_f2b4<<<dim3(1024), 256, 0, stream>>>(Wy, Wyb, 262144);
  k_transpose_bf16<<<dim3(32, 32), dim3(32, 8), 0, stream>>>(Whz, WhzT);

  // Mz = Wxz @ Whz  -> Wrec rows 1024..2047
  gemm_bt<1><<<dim3(8, 8), 256, 0, stream>>>(Wcat + 1024 * 1024, WhzT, nullptr, nullptr,
                                             Wrec + (size_t)1024 * 1024, 1024);
  // xhz = x @ [Wxh;Wxz]^T + [bh;bz], time-major
  gemm_bt<0><<<dim3(16, 256), 256, 0, stream>>>(xb, Wcat, bh, bz, xhz, 1024);

  // cooperative launch; 128 KB dynamic LDS
  hipFuncSetAttribute((const void*)scan_out_k,
                      hipFuncAttributeMaxDynamicSharedMemorySize, SCAN_LDS_BYTES);
  const unsigned short* xhz_c = xhz;
  const unsigned short* Wrec_c = Wrec;
  const unsigned short* Wyb_c = Wyb;
  const float* by_c = by;
  void* kargs[] = {(void*)&xhz_c, (void*)&Wrec_c, (void*)&Wyb_c, (void*)&by_c,
                   (void*)&hb0, (void*)&hb1, (void*)&flags, (void*)&out};
  hipLaunchCooperativeKernel((void*)scan_out_k, dim3(SCAN_BLOCKS), dim3(1024),
                             kargs, SCAN_LDS_BYTES, stream);
}

// Round 6
// 3382.479 us; speedup vs baseline: 1.6545x; 1.6545x over previous
//
#include <hip/hip_runtime.h>

// Problem constants (fixed by the reference): B=64, T=512, D=1024, R=1024, O=1024
#define BB 64
#define TT 512
#define DD 1024
#define RR 1024

#define SCAN_BLOCKS 32
#define HS_STRIDE 1032            // staged h row stride in bf16 (1024 + 8 pad)
#define SCAN_LDS_BYTES (64 * HS_STRIDE * 2)   // 132096 B; red overlay needs 69632

typedef __bf16 bf16x8 __attribute__((ext_vector_type(8)));
typedef float f32x4 __attribute__((ext_vector_type(4)));
typedef unsigned short us4 __attribute__((ext_vector_type(4)));
typedef unsigned int u32x4 __attribute__((ext_vector_type(4)));

__device__ inline unsigned short f2bf(float f) {
  unsigned int u = __float_as_uint(f);
  u = (u + 0x7fffu + ((u >> 16) & 1u)) >> 16;   // RNE
  return (unsigned short)u;
}
__device__ inline float bf2f(unsigned short b) {
  return __uint_as_float(((unsigned int)b) << 16);
}

// Coherent 16B load/store: sc0 sc1 -> bypass non-coherent L1/L2, served at L3.
__device__ inline u32x4 ld16_sc(const void* p) {
  u32x4 r;
  asm volatile("global_load_dwordx4 %0, %1, off sc0 sc1"
               : "=v"(r) : "v"(p) : "memory");
  return r;
}
__device__ inline void st16_sc(void* p, u32x4 v) {
  asm volatile("global_store_dwordx4 %0, %1, off sc0 sc1" :: "v"(p), "v"(v) : "memory");
}

// ---- fp32 -> bf16 vectorized convert (n4 = n/4 groups) ----
__global__ void k_f2b4(const float* __restrict__ in, unsigned short* __restrict__ out, int n4) {
  int i = blockIdx.x * blockDim.x + threadIdx.x;
  if (i < n4) {
    const float4 v = ((const float4*)in)[i];
    us4 o;
    o.x = f2bf(v.x); o.y = f2bf(v.y); o.z = f2bf(v.z); o.w = f2bf(v.w);
    ((us4*)out)[i] = o;
  }
}

// ---- transpose 1024x1024 fp32 -> bf16 (out[j][k] = in[k][j]) ----
__global__ __launch_bounds__(256) void k_transpose_bf16(
    const float* __restrict__ in, unsigned short* __restrict__ out) {
  __shared__ float tile[32][33];
  const int bx = blockIdx.x * 32, by0 = blockIdx.y * 32;
  const int tx = threadIdx.x, ty = threadIdx.y;  // block (32,8)
#pragma unroll
  for (int r = 0; r < 32; r += 8)
    tile[ty + r][tx] = in[(size_t)(by0 + ty + r) * 1024 + bx + tx];
  __syncthreads();
#pragma unroll
  for (int r = 0; r < 32; r += 8)
    out[(size_t)(bx + ty + r) * 1024 + by0 + tx] = f2bf(tile[tx][ty + r]);
}

// ---- async global->LDS, 16B per lane (plain cached; GEMM prelude only) ----
__device__ inline void gload_lds16(const unsigned short* g, unsigned short* l) {
  __builtin_amdgcn_global_load_lds(
      (const __attribute__((address_space(1))) unsigned int*)g,
      (__attribute__((address_space(3))) unsigned int*)l, 16, 0, 0);
}

// ---- bf16 GEMM, C[m,n] = sum_k A[m,k]*B[n,k], 128x128 tile, BK=32 ----
// EPI==0: out = xhz time-major [T][B][2048] bf16, bias folded (bh n<1024, bz else)
// EPI==1: out[m*1024+n] bf16 (Mz into Wrec rows 1024..2047)
template <int EPI>
__global__ __launch_bounds__(256) void gemm_bt(
    const unsigned short* __restrict__ A,
    const unsigned short* __restrict__ Bm,
    const float* __restrict__ bias_h,
    const float* __restrict__ bias_z,
    unsigned short* __restrict__ outb, int K) {
  __shared__ __attribute__((aligned(16))) unsigned short As[128 * 32];
  __shared__ __attribute__((aligned(16))) unsigned short Bs[128 * 32];
  const int tid = threadIdx.x;
  const int m0 = blockIdx.y * 128, n0 = blockIdx.x * 128;
  const int lane = tid & 63, wid = tid >> 6;
  const int l16 = lane & 15, quad = lane >> 4;
  const int wm = (wid & 1) * 64, wn = (wid >> 1) * 64;

  f32x4 acc[4][4] = {};

  const int c0 = tid, c1 = 256 + tid;
  const int rowA0 = c0 >> 2, colA0 = (c0 & 3) << 3;
  const int rowA1 = c1 >> 2, colA1 = (c1 & 3) << 3;

  for (int kk = 0; kk < K; kk += 32) {
    __syncthreads();
    gload_lds16(A + (size_t)(m0 + rowA0) * K + kk + colA0, As + c0 * 8);
    gload_lds16(A + (size_t)(m0 + rowA1) * K + kk + colA1, As + c1 * 8);
    gload_lds16(Bm + (size_t)(n0 + rowA0) * K + kk + colA0, Bs + c0 * 8);
    gload_lds16(Bm + (size_t)(n0 + rowA1) * K + kk + colA1, Bs + c1 * 8);
    __syncthreads();
    bf16x8 af[4], bfr[4];
#pragma unroll
    for (int i = 0; i < 4; ++i) {
      af[i] = *(const bf16x8*)&As[(wm + i * 16 + l16) * 32 + quad * 8];
      bfr[i] = *(const bf16x8*)&Bs[(wn + i * 16 + l16) * 32 + quad * 8];
    }
#pragma unroll
    for (int i = 0; i < 4; ++i)
#pragma unroll
      for (int j = 0; j < 4; ++j)
        acc[i][j] = __builtin_amdgcn_mfma_f32_16x16x32_bf16(af[i], bfr[j], acc[i][j], 0, 0, 0);
  }

#pragma unroll
  for (int i = 0; i < 4; ++i) {
#pragma unroll
    for (int j = 0; j < 4; ++j) {
#pragma unroll
      for (int r = 0; r < 4; ++r) {
        const int m = m0 + wm + i * 16 + quad * 4 + r;
        const int n = n0 + wn + j * 16 + l16;
        float v = acc[i][j][r];
        if (EPI == 0) {
          v += (n < 1024) ? bias_h[n] : bias_z[n - 1024];
          const int b = m >> 9;          // m = b*T + t, T=512
          const int t = m & 511;
          outb[((size_t)(t * 64 + b) << 11) + n] = f2bf(v);
        } else {
          outb[(size_t)m * 1024 + n] = f2bf(v);
        }
      }
    }
  }
}

// ---- persistent scan over T=512 steps + output GEMM ----
// 32 blocks x 1024 threads. 16 waves = 4 K-slices (ks) x 2 m-halves (ms) x
// 2 n-halves (ns). Block g owns h-cols [g*32,+32); local n-col c<32 -> Whh
// row i0+c (ph), c>=32 -> Mz row 1024+i0+(c-32) (pz).
//
// Round-6: revert r5's uncoalesced LDS-DMA staging (8x packet inflation,
// serialized DMA-port writes) to r4's coalesced ld16_sc->ds_write staging,
// remapped per-wave: wave w stages cols [w*64,+64) for all 64 rows, so it
// polls exactly 2 producer flags (2w, 2w+1) before issuing its loads.
// Keep (4,2,2) tiling (A-read feeds 2 MFMAs; 256 KB/blk/step A-traffic) with
// row-major padded LDS (row offset = 4 banks -> only free 2-way aliasing).
__global__ __launch_bounds__(1024) void scan_out_k(
    const unsigned short* __restrict__ xhz,   // [T][B][2048] bf16
    const unsigned short* __restrict__ Wrec,  // [2048][1024] bf16 (Whh ; Mz)
    const unsigned short* __restrict__ Wyb,   // [1024][1024] bf16
    const float* __restrict__ by,
    unsigned short* __restrict__ hb0, unsigned short* __restrict__ hb1,
    unsigned int* __restrict__ flags,
    float* __restrict__ out) {
  extern __shared__ char smem[];
  unsigned short* hs = (unsigned short*)smem;   // [64][HS_STRIDE] bf16
  float* red = (float*)smem;                    // overlay [4][64][68] f32

  const int tid = threadIdx.x, g = blockIdx.x;
  const int lane = tid & 63, w = tid >> 6;
  const int l16 = lane & 15, quad = lane >> 4;
  const int ks = w >> 2, ms = (w >> 1) & 1, ns = w & 1;
  const int kw = ks * 256;
  const int i0 = g * 32;

  // loop-invariant B fragments: bfr[s][nf] (plain cached loads)
  bf16x8 bfr[8][2];
#pragma unroll
  for (int nf = 0; nf < 2; ++nf) {
    const int brow = (ns == 0) ? (i0 + nf * 16 + l16) : (1024 + i0 + nf * 16 + l16);
    const unsigned short* Bp = Wrec + (size_t)brow * 1024 + kw + quad * 8;
#pragma unroll
    for (int s = 0; s < 8; ++s) bfr[s][nf] = *(const bf16x8*)(Bp + s * 32);
  }

  // staging map: wave w stages cols [w*64, w*64+64) for rows (lane>>3)+8j.
  // Lanes 0..7 cover one contiguous 128B row-segment -> coalesced.
  const int srow = lane >> 3;          // +8j
  const int scc = (lane & 7) * 8;      // 16B chunk within 64-col span (elems)
  const size_t goff = (size_t)srow * 1024 + w * 64 + scc;
  unsigned short* ldst = hs + (size_t)srow * HS_STRIDE + w * 64 + scc;

  // producer poll: wave w's staged cols come from blocks 2w, 2w+1
  const int pidx = 2 * w + (lane & 1);
  const bool polls = (lane < 2);

  // elementwise ownership (threads 0..255): b = tid>>2, cols i0+oc8..+8
  const int eb = tid >> 2, oc8 = (tid & 3) * 8;
  float hold[8] = {0.f, 0.f, 0.f, 0.f, 0.f, 0.f, 0.f, 0.f};

  const unsigned short* hbc = hb0;
  unsigned short* hbn = hb1;

  for (int tt = 0; tt < TT; ++tt) {
    // ---- per-wave producer poll: cols [w*64,+64) of h_tt ready? ----
    {
      const unsigned int tgt = (unsigned int)tt;
      unsigned int v;
      do {
        v = polls ? __hip_atomic_load(&flags[pidx], __ATOMIC_RELAXED, __HIP_MEMORY_SCOPE_AGENT)
                  : 0xffffffffu;
      } while (__any(v < tgt));
    }
    // ---- coalesced coherent stage: 8 x 16B per lane -> VGPRs -> LDS ----
    u32x4 tmp[8];
#pragma unroll
    for (int j = 0; j < 8; ++j)
      tmp[j] = ld16_sc(hbc + goff + (size_t)j * 8 * 1024);
    // xhz prefetch (plain cached)
    u32x4 xh8 = {}, xz8 = {};
    if (tid < 256) {
      const size_t xrow = ((size_t)(tt * 64 + eb)) << 11;
      xh8 = *(const u32x4*)(xhz + xrow + i0 + oc8);
      xz8 = *(const u32x4*)(xhz + xrow + 1024 + i0 + oc8);
    }
    asm volatile("s_waitcnt vmcnt(0)" ::: "memory");
#pragma unroll
    for (int j = 0; j < 8; ++j)
      *(u32x4*)(ldst + (size_t)j * 8 * HS_STRIDE) = tmp[j];
    __syncthreads();   // hs fully staged

    // ---- MFMA (4,2,2): each A-read feeds 2 n-frags ----
    f32x4 acc[2][2] = {};
#pragma unroll
    for (int s = 0; s < 8; ++s) {
#pragma unroll
      for (int mt = 0; mt < 2; ++mt) {
        const int row = ms * 32 + mt * 16 + l16;
        const bf16x8 afr = *(const bf16x8*)(hs + (size_t)row * HS_STRIDE + kw + s * 32 + quad * 8);
        acc[mt][0] = __builtin_amdgcn_mfma_f32_16x16x32_bf16(afr, bfr[s][0], acc[mt][0], 0, 0, 0);
        acc[mt][1] = __builtin_amdgcn_mfma_f32_16x16x32_bf16(afr, bfr[s][1], acc[mt][1], 0, 0, 0);
      }
    }
    __syncthreads();   // hs reads done; safe to overlay red

    // ---- K-partials into LDS: red[ks][m 0..63][c 0..63], stride 68 ----
#pragma unroll
    for (int mt = 0; mt < 2; ++mt)
#pragma unroll
      for (int nf = 0; nf < 2; ++nf)
#pragma unroll
        for (int r = 0; r < 4; ++r)
          red[(size_t)(ks * 64 + ms * 32 + mt * 16 + quad * 4 + r) * 68 +
              ns * 32 + nf * 16 + l16] = acc[mt][nf][r];
    __syncthreads();

    // ---- elementwise update: threads 0..255, 8 cols each ----
    if (tid < 256) {
      float ph[8] = {}, pz[8] = {};
#pragma unroll
      for (int k = 0; k < 4; ++k) {
        const float* rb = red + (size_t)(k * 64 + eb) * 68;
        const float4 a0 = *(const float4*)(rb + oc8);
        const float4 a1 = *(const float4*)(rb + oc8 + 4);
        const float4 c0 = *(const float4*)(rb + 32 + oc8);
        const float4 c1 = *(const float4*)(rb + 32 + oc8 + 4);
        ph[0] += a0.x; ph[1] += a0.y; ph[2] += a0.z; ph[3] += a0.w;
        ph[4] += a1.x; ph[5] += a1.y; ph[6] += a1.z; ph[7] += a1.w;
        pz[0] += c0.x; pz[1] += c0.y; pz[2] += c0.z; pz[3] += c0.w;
        pz[4] += c1.x; pz[5] += c1.y; pz[6] += c1.z; pz[7] += c1.w;
      }
      const unsigned short* xhp = (const unsigned short*)&xh8;
      const unsigned short* xzp = (const unsigned short*)&xz8;
      unsigned short hb16[8];
#pragma unroll
      for (int j = 0; j < 8; ++j) {
        const float xh = bf2f(xhp[j]);
        const float xz = bf2f(xzp[j]);
        const float z = 1.0f / (1.0f + __expf(-(xz + pz[j])));
        const float hbv = fmaxf(xh + ph[j], 0.0f);
        hold[j] = z * hold[j] + (1.0f - z) * hbv;
        hb16[j] = f2bf(hold[j]);
      }
      u32x4 pk;
#pragma unroll
      for (int j = 0; j < 4; ++j)
        pk[j] = (unsigned int)hb16[2 * j] | ((unsigned int)hb16[2 * j + 1] << 16);
      st16_sc(hbn + (size_t)eb * 1024 + i0 + oc8, pk);
    }
    __syncthreads();   // drains h' stores (vmcnt) before the flag
    if (tid == 0)
      __hip_atomic_store(&flags[g], (unsigned int)(tt + 1),
                         __ATOMIC_RELAXED, __HIP_MEMORY_SCOPE_AGENT);

    const unsigned short* tc = hbc; hbc = hbn; hbn = (unsigned short*)tc;
  }

  // ---- epilogue: out = h_final @ Wy^T + by (h_512 in hbc == hb0) ----
  {
    const unsigned int tgt = (unsigned int)TT;
    unsigned int v;
    do {
      v = polls ? __hip_atomic_load(&flags[pidx], __ATOMIC_RELAXED, __HIP_MEMORY_SCOPE_AGENT)
                : 0xffffffffu;
    } while (__any(v < tgt));
  }
  {
    u32x4 tmp[8];
#pragma unroll
    for (int j = 0; j < 8; ++j)
      tmp[j] = ld16_sc(hbc + goff + (size_t)j * 8 * 1024);
    asm volatile("s_waitcnt vmcnt(0)" ::: "memory");
#pragma unroll
    for (int j = 0; j < 8; ++j)
      *(u32x4*)(ldst + (size_t)j * 8 * HS_STRIDE) = tmp[j];
  }
  __syncthreads();

  // wave (ks,ms,ns): out-cols i0 + ns*16 + l16, m-rows ms*32..
  {
    const int ocol = i0 + ns * 16 + l16;
    const unsigned short* Byp = Wyb + (size_t)ocol * 1024 + kw + quad * 8;
    bf16x8 bfr2[8];
#pragma unroll
    for (int s = 0; s < 8; ++s) bfr2[s] = *(const bf16x8*)(Byp + s * 32);
    f32x4 acc2[2] = {};
#pragma unroll
    for (int s = 0; s < 8; ++s) {
#pragma unroll
      for (int mt = 0; mt < 2; ++mt) {
        const int row = ms * 32 + mt * 16 + l16;
        const bf16x8 afr = *(const bf16x8*)(hs + (size_t)row * HS_STRIDE + kw + s * 32 + quad * 8);
        acc2[mt] = __builtin_amdgcn_mfma_f32_16x16x32_bf16(afr, bfr2[s], acc2[mt], 0, 0, 0);
      }
    }
    __syncthreads();   // all hs reads done; overlay red2
    float* red2 = (float*)smem;   // [4][64][36]
#pragma unroll
    for (int mt = 0; mt < 2; ++mt)
#pragma unroll
      for (int r = 0; r < 4; ++r)
        red2[(size_t)(ks * 64 + ms * 32 + mt * 16 + quad * 4 + r) * 36 + ns * 16 + l16] = acc2[mt][r];
  }
  __syncthreads();
  {
    float* red2 = (float*)smem;
    const int b = tid >> 4, oc2 = (tid & 15) * 2;
    float o0 = by[i0 + oc2], o1 = by[i0 + oc2 + 1];
#pragma unroll
    for (int k = 0; k < 4; ++k) {
      const float* rb = red2 + (size_t)(k * 64 + b) * 36;
      o0 += rb[oc2]; o1 += rb[oc2 + 1];
    }
    float2 ov; ov.x = o0; ov.y = o1;
    *(float2*)(out + (size_t)b * 1024 + i0 + oc2) = ov;
  }
}

extern "C" void kernel_launch(void* const* d_in, const int* in_sizes, int n_in,
                              void* d_out, int out_size, void* d_ws, size_t ws_size,
                              hipStream_t stream) {
  const float* x = (const float*)d_in[0];
  const float* Wxh = (const float*)d_in[1];
  const float* bh = (const float*)d_in[2];
  const float* Whh = (const float*)d_in[3];
  const float* Wxz = (const float*)d_in[4];
  const float* bz = (const float*)d_in[5];
  const float* Whz = (const float*)d_in[6];
  const float* Wy = (const float*)d_in[7];
  const float* by = (const float*)d_in[8];
  float* out = (float*)d_out;

  char* ws = (char*)d_ws;
  size_t off = 0;
  auto alloc = [&](size_t bytes) -> void* {
    void* p = ws + off;
    off += (bytes + 255) & ~(size_t)255;
    return p;
  };
  const size_t nX = (size_t)BB * TT * DD;  // 33554432
  unsigned short* xb = (unsigned short*)alloc(nX * 2);                  // x bf16
  unsigned short* Wcat = (unsigned short*)alloc((size_t)2048 * 1024 * 2);  // [Wxh;Wxz]
  unsigned short* WhzT = (unsigned short*)alloc((size_t)1024 * 1024 * 2);  // Whz^T
  unsigned short* Wrec = (unsigned short*)alloc((size_t)2048 * 1024 * 2);  // [Whh;Mz]
  unsigned short* Wyb = (unsigned short*)alloc((size_t)1024 * 1024 * 2);   // Wy bf16
  unsigned short* xhz = (unsigned short*)alloc((size_t)TT * BB * 2048 * 2);  // 128 MB
  unsigned short* hb0 = (unsigned short*)alloc((size_t)BB * RR * 2);
  unsigned short* hb1 = (unsigned short*)alloc((size_t)BB * RR * 2);
  unsigned int* flags = (unsigned int*)alloc(1024);

  hipMemsetAsync(hb0, 0, (size_t)BB * RR * 2, stream);
  hipMemsetAsync(flags, 0, 1024, stream);

  // weight / input conversions
  k_f2b4<<<dim3((unsigned)(nX / 4 / 256)), 256, 0, stream>>>(x, xb, (int)(nX / 4));
  k_f2b4<<<dim3(1024), 256, 0, stream>>>(Wxh, Wcat, 262144);
  k_f2b4<<<dim3(1024), 256, 0, stream>>>(Wxz, Wcat + 1024 * 1024, 262144);
  k_f2b4<<<dim3(1024), 256, 0, stream>>>(Whh, Wrec, 262144);
  k_f2b4<<<dim3(1024), 256, 0, stream>>>(Wy, Wyb, 262144);
  k_transpose_bf16<<<dim3(32, 32), dim3(32, 8), 0, stream>>>(Whz, WhzT);

  // Mz = Wxz @ Whz  -> Wrec rows 1024..2047
  gemm_bt<1><<<dim3(8, 8), 256, 0, stream>>>(Wcat + 1024 * 1024, WhzT, nullptr, nullptr,
                                             Wrec + (size_t)1024 * 1024, 1024);
  // xhz = x @ [Wxh;Wxz]^T + [bh;bz], time-major
  gemm_bt<0><<<dim3(16, 256), 256, 0, stream>>>(xb, Wcat, bh, bz, xhz, 1024);

  // cooperative launch; 129 KB dynamic LDS
  hipFuncSetAttribute((const void*)scan_out_k,
                      hipFuncAttributeMaxDynamicSharedMemorySize, SCAN_LDS_BYTES);
  const unsigned short* xhz_c = xhz;
  const unsigned short* Wrec_c = Wrec;
  const unsigned short* Wyb_c = Wyb;
  const float* by_c = by;
  void* kargs[] = {(void*)&xhz_c, (void*)&Wrec_c, (void*)&Wyb_c, (void*)&by_c,
                   (void*)&hb0, (void*)&hb1, (void*)&flags, (void*)&out};
  hipLaunchCooperativeKernel((void*)scan_out_k, dim3(SCAN_BLOCKS), dim3(1024),
                             kargs, SCAN_LDS_BYTES, stream);
}